// Round 19
// baseline (145.684 us; speedup 1.0000x reference)
//
#include <hip/hip_runtime.h>

typedef _Float16 f16;
typedef _Float16 f16x8 __attribute__((ext_vector_type(8)));
typedef _Float16 f16x4 __attribute__((ext_vector_type(4)));
typedef _Float16 f16x2 __attribute__((ext_vector_type(2)));
typedef __fp16   h16x2 __attribute__((ext_vector_type(2)));   // builtin's native type
typedef float    f32x16 __attribute__((ext_vector_type(16)));
typedef unsigned int u32;

typedef const __attribute__((address_space(1))) void GVOID;
typedef __attribute__((address_space(3))) void LVOID;

static __device__ __forceinline__ f32x16 mfma32(f16x8 a, f16x8 b, f32x16 c) {
  return __builtin_amdgcn_mfma_f32_32x32x16_f16(a, b, c, 0, 0, 0);
}
static __device__ __forceinline__ void gl_lds16(const f16* g, f16* l) {
  __builtin_amdgcn_global_load_lds((GVOID*)g, (LVOID*)l, 16, 0, 0);
}
// single-instruction packed f32x2 -> f16x2 (RTZ); bit layout lo=a, hi=b
static __device__ __forceinline__ u32 pk(float a, float b) {
  union { h16x2 h; u32 w; } u;
  u.h = __builtin_amdgcn_cvt_pkrtz(a, b);
  return u.w;
}
static __device__ __forceinline__ u32 pkh(f16 a, f16 b) {
  union { f16x2 h; u32 w; } u;
  u.h[0] = a; u.h[1] = b;
  return u.w;
}
// A-frag builder: 8 P values -> f16x8 = P[q][kv=8*hi+j] via permlane32_swap.
static __device__ __forceinline__ f16x8 mkfrag(float a0, float a1, float a2, float a3,
                                               float a4, float a5, float a6, float a7) {
  u32 c01 = pk(a0, a1), c23 = pk(a2, a3), c45 = pk(a4, a5), c67 = pk(a6, a7);
  asm("v_permlane32_swap_b32 %0, %1" : "+v"(c01), "+v"(c45));
  asm("v_permlane32_swap_b32 %0, %1" : "+v"(c23), "+v"(c67));
  union { f16x8 h; u32 w[4]; } u;
  u.w[0] = c01; u.w[1] = c23; u.w[2] = c45; u.w[3] = c67;
  return u.h;
}

// ---------------------------------------------------------------------------
// f32 -> f16 convert, weights only (wa 393216 + wp 262144 = 655360 elems)
// ---------------------------------------------------------------------------
__global__ __launch_bounds__(256)
void cvt_w(const float* __restrict__ wa, f16* __restrict__ wah,
           const float* __restrict__ wp, f16* __restrict__ wph) {
  int i = (blockIdx.x * 256 + threadIdx.x) * 8;
  const float* s; f16* d;
  if (i < 393216) { s = wa + i; d = wah + i; }
  else            { int j = i - 393216; s = wp + j; d = wph + j; }
  float4 v0 = *(const float4*)(s);
  float4 v1 = *(const float4*)(s + 4);
  f16x8 h;
  h[0] = (f16)v0.x; h[1] = (f16)v0.y; h[2] = (f16)v0.z; h[3] = (f16)v0.w;
  h[4] = (f16)v1.x; h[5] = (f16)v1.y; h[6] = (f16)v1.z; h[7] = (f16)v1.w;
  *(f16x8*)d = h;
}

// ---------------------------------------------------------------------------
// GEMM1 fused-A: qkv = x(f32) @ wa_h^T + b_attn.  r16 gemm256 structure;
// B staged via gl_lds (issued first), A loaded f32->regs, cvt_pkrtz,
// swizzled ds_write (same slot mapping as the gl_lds pre-swizzle).
// LDS stays 48KB single-buffered -> 2 blocks/CU.
// ---------------------------------------------------------------------------
__global__ __launch_bounds__(512)
void gemm1fa(const float* __restrict__ A, const f16* __restrict__ B,
             const float* __restrict__ bias, f16* __restrict__ outH) {
  constexpr int KD = 256, NDIM = 1536, NB = 12;
  __shared__ __align__(16) f16 As[256 * 64];
  __shared__ __align__(16) f16 Bs[128 * 64];

  const int nwg = gridDim.x, orig = blockIdx.x;
  const int xcd = orig & 7, loc = orig >> 3;
  const int qq = nwg >> 3, rr8 = nwg & 7;
  const int g = (xcd < rr8 ? xcd * (qq + 1) : rr8 * (qq + 1) + (xcd - rr8) * qq) + loc;
  const int mb = g / NB, nb = g - mb * NB;
  const int m0 = mb * 256, n0 = nb * 128;

  const int tid = threadIdx.x, wid = tid >> 6;
  const int l31 = tid & 31, hi = (tid >> 5) & 1;
  const int wm = (wid >> 1) * 64, wn = (wid & 1) * 64;

  f32x16 acc[2][2] = {};

  for (int k0 = 0; k0 < KD; k0 += 64) {
    __syncthreads();
    // B first: gl_lds flies while A loads/converts
#pragma unroll
    for (int i = 0; i < 2; ++i) {
      int c = i * 512 + tid, row = c >> 3;
      int col = 8 * ((c & 7) ^ (row & 7));
      gl_lds16(B + (size_t)(n0 + row) * KD + k0 + col, &Bs[c * 8]);
    }
    // A: issue all f32 loads, then convert + swizzled ds_write
    float4 av[4][2];
#pragma unroll
    for (int i = 0; i < 4; ++i) {
      int c = i * 512 + tid, row = c >> 3, kc = k0 + 8 * (c & 7);
      const float* p = A + (size_t)(m0 + row) * KD + kc;
      av[i][0] = *(const float4*)p;
      av[i][1] = *(const float4*)(p + 4);
    }
#pragma unroll
    for (int i = 0; i < 4; ++i) {
      int c = i * 512 + tid, row = c >> 3;
      int slot = (c & 7) ^ (row & 7);
      union { f16x8 h; u32 w[4]; } u;
      u.w[0] = pk(av[i][0].x, av[i][0].y);
      u.w[1] = pk(av[i][0].z, av[i][0].w);
      u.w[2] = pk(av[i][1].x, av[i][1].y);
      u.w[3] = pk(av[i][1].z, av[i][1].w);
      *(f16x8*)&As[row * 64 + 8 * slot] = u.h;
    }
    __syncthreads();                       // drains B gl_lds + A ds_writes
#pragma unroll
    for (int kk = 0; kk < 4; ++kk) {
      f16x8 af[2], bf[2];
#pragma unroll
      for (int t = 0; t < 2; ++t) {
        int ra = wm + t * 32 + l31;
        af[t] = *(const f16x8*)&As[ra * 64 + 8 * ((2 * kk + hi) ^ (ra & 7))];
        int rb = wn + t * 32 + l31;
        bf[t] = *(const f16x8*)&Bs[rb * 64 + 8 * ((2 * kk + hi) ^ (rb & 7))];
      }
#pragma unroll
      for (int ms = 0; ms < 2; ++ms)
#pragma unroll
        for (int ns = 0; ns < 2; ++ns)
          acc[ms][ns] = mfma32(af[ms], bf[ns], acc[ms][ns]);
    }
  }

  float bv[2];
  bv[0] = bias[n0 + wn + l31];
  bv[1] = bias[n0 + wn + 32 + l31];
#pragma unroll
  for (int ms = 0; ms < 2; ++ms)
#pragma unroll
    for (int ns = 0; ns < 2; ++ns)
#pragma unroll
      for (int r = 0; r < 16; ++r) {
        int mrow = (r & 3) + 8 * (r >> 2) + 4 * hi;
        int m_g = m0 + wm + ms * 32 + mrow;
        int n_g = n0 + wn + ns * 32 + l31;
        outH[(size_t)m_g * NDIM + n_g] = (f16)(acc[ms][ns][r] + bv[ns]);
      }
}

// ---------------------------------------------------------------------------
// GEMM3 [r17 exact]: 128x128, BK=64, 8 waves, dbuf, counted vmcnt.
// ---------------------------------------------------------------------------
template<int EPI, int KD, int NDIM>
__global__ __launch_bounds__(512)
void gemmdb(const f16* __restrict__ A, const f16* __restrict__ B,
            const float* __restrict__ bias, f16* __restrict__ outH,
            float* __restrict__ outF) {
  constexpr int KT = KD / 64;
  constexpr int ABUF = 128 * 64, BUFSZ = 2 * ABUF;
  __shared__ __align__(16) f16 lds[2 * BUFSZ];

  const int nwg = gridDim.x, orig = blockIdx.x;
  const int xcd = orig & 7, loc = orig >> 3;
  const int qq = nwg >> 3, rr8 = nwg & 7;
  const int gb = (xcd < rr8 ? xcd * (qq + 1) : rr8 * (qq + 1) + (xcd - rr8) * qq) + loc;
  constexpr int NB = NDIM / 128;
  const int mb = gb / NB, nb = gb - mb * NB;
  const int m0 = mb * 128, n0 = nb * 128;

  const int tid = threadIdx.x, wid = tid >> 6;
  const int l31 = tid & 31, hi = (tid >> 5) & 1;
  const int wm = (wid >> 2) * 64, wn = (wid & 3) * 32;

  f32x16 acc[2] = {};

  const int c0 = tid, c1 = 512 + tid;
  const int r0 = c0 >> 3, col0 = 8 * ((c0 & 7) ^ (r0 & 7));
  const int r1 = c1 >> 3, col1 = 8 * ((c1 & 7) ^ (r1 & 7));

  auto STAGE = [&](int t, int bufi) {
    const int k0 = t * 64;
    f16* Ab = &lds[bufi * BUFSZ];
    f16* Bb = Ab + ABUF;
    gl_lds16(A + (size_t)(m0 + r0) * KD + k0 + col0, &Ab[c0 * 8]);
    gl_lds16(A + (size_t)(m0 + r1) * KD + k0 + col1, &Ab[c1 * 8]);
    gl_lds16(B + (size_t)(n0 + r0) * KD + k0 + col0, &Bb[c0 * 8]);
    gl_lds16(B + (size_t)(n0 + r1) * KD + k0 + col1, &Bb[c1 * 8]);
  };

  STAGE(0, 0);
  int cur = 0;
#pragma unroll
  for (int t = 0; t < KT; ++t) {
    if (t + 1 < KT) {
      STAGE(t + 1, cur ^ 1);
      asm volatile("s_waitcnt vmcnt(4)" ::: "memory");
    } else {
      asm volatile("s_waitcnt vmcnt(0)" ::: "memory");
    }
    __builtin_amdgcn_sched_barrier(0);
    __builtin_amdgcn_s_barrier();

    const f16* Ab = &lds[cur * BUFSZ];
    const f16* Bb = Ab + ABUF;
    __builtin_amdgcn_s_setprio(1);
#pragma unroll
    for (int kk = 0; kk < 4; ++kk) {
      int rb = wn + l31;
      f16x8 bf = *(const f16x8*)&Bb[rb * 64 + 8 * ((2 * kk + hi) ^ (rb & 7))];
      int ra0 = wm + l31, ra1 = wm + 32 + l31;
      f16x8 af0 = *(const f16x8*)&Ab[ra0 * 64 + 8 * ((2 * kk + hi) ^ (ra0 & 7))];
      f16x8 af1 = *(const f16x8*)&Ab[ra1 * 64 + 8 * ((2 * kk + hi) ^ (ra1 & 7))];
      acc[0] = mfma32(af0, bf, acc[0]);
      acc[1] = mfma32(af1, bf, acc[1]);
    }
    __builtin_amdgcn_s_setprio(0);
    __builtin_amdgcn_s_barrier();
    cur ^= 1;
  }

  float bv = bias[n0 + wn + l31];
#pragma unroll
  for (int ms = 0; ms < 2; ++ms)
#pragma unroll
    for (int r = 0; r < 16; ++r) {
      int mrow = (r & 3) + 8 * (r >> 2) + 4 * hi;
      int m_g = m0 + wm + ms * 32 + mrow;
      int n_g = n0 + wn + l31;
      float v = acc[ms][r] + bv;
      if (EPI == 0) outH[(size_t)m_g * NDIM + n_g] = (f16)v;
      else          outF[(size_t)m_g * NDIM + n_g] = v;
    }
}

// ---------------------------------------------------------------------------
// Flash attention [r17 structure]: full unroll, lane-local l, kt==6-only
// clamps; pk() now single v_cvt_pkrtz (-32 VALU/kt in mkfrag).
// ---------------------------------------------------------------------------
__global__ __launch_bounds__(512, 4)
void attn_kern(const f16* __restrict__ qkv, f16* __restrict__ Yg) {
  __shared__ __align__(16) f16 Kl[2][64 * 64];
  __shared__ __align__(16) f16 VT[2][64 * 64];
  const int id = blockIdx.x;
  const int g = (id & 7) * 128 + (id >> 3);
  const int bh = g >> 1, qt = g & 1;
  const int b = bh >> 3, h = bh & 7;
  const int tid = threadIdx.x, w = tid >> 6;
  const int l31 = tid & 31, hi = (tid & 63) >> 5, e7 = l31 & 7;

  const f16* base  = qkv + (size_t)b * 500 * 1536 + h * 64;
  const f16* Kbase = base + 512;
  const f16* Vbase = base + 1024;

  const int q = qt * 256 + w * 32 + l31;
  const int qc = q < 500 ? q : 499;
  f16x8 qf[4];
  const f16* qp = base + (size_t)qc * 1536 + hi * 8;
#pragma unroll
  for (int ds = 0; ds < 4; ++ds) qf[ds] = *(const f16x8*)(qp + 16 * ds);
  const f16 qs = (f16)(0.125f * 1.44269504f);
#pragma unroll
  for (int ds = 0; ds < 4; ++ds)
#pragma unroll
    for (int j = 0; j < 8; ++j) qf[ds][j] *= qs;

  f32x16 O0 = {}, O1 = {};
  float l = 0.f;

  const int krow = tid >> 3, kcol = 8 * ((tid & 7) ^ (krow & 7));
  const int kvp = (tid & 31) * 2, d4 = (tid >> 5) * 4;
  f16x4 va, vb;
  const f16x4 VZ4 = {};

  {
    gl_lds16(Kbase + (size_t)krow * 1536 + kcol, &Kl[0][tid * 8]);
    const f16* vp0 = Vbase + (size_t)kvp * 1536 + d4;
    va = *(const f16x4*)vp0; vb = *(const f16x4*)(vp0 + 1536);
#pragma unroll
    for (int dd = 0; dd < 4; ++dd) {
      int d = d4 + dd;
      *(u32*)&VT[0][d * 64 + (kvp ^ ((d & 7) << 3))] = pkh(va[dd], vb[dd]);
    }
    __syncthreads();
  }

#pragma unroll
  for (int kt = 0; kt < 8; ++kt) {
    const int cur = kt & 1, nxt = cur ^ 1;
    if (kt < 7) {
      const int kvn = (kt + 1) * 64;
      int kr = kvn + krow;
      if (kt == 6) kr = kr < 500 ? kr : 499;
      gl_lds16(Kbase + (size_t)kr * 1536 + kcol, &Kl[nxt][tid * 8]);
      int kv = kvn + kvp;
      if (kt == 6) {
        int kc0 = kv < 500 ? kv : 499, kc1 = kv + 1 < 500 ? kv + 1 : 499;
        va = *(const f16x4*)(Vbase + (size_t)kc0 * 1536 + d4);
        vb = *(const f16x4*)(Vbase + (size_t)kc1 * 1536 + d4);
        if (kv >= 500) va = VZ4;
        if (kv + 1 >= 500) vb = VZ4;
      } else {
        va = *(const f16x4*)(Vbase + (size_t)kv * 1536 + d4);
        vb = *(const f16x4*)(Vbase + (size_t)(kv + 1) * 1536 + d4);
      }
    }

    f32x16 s0 = {}, s1 = {};
    __builtin_amdgcn_s_setprio(1);
#pragma unroll
    for (int ds = 0; ds < 4; ++ds) {
      f16x8 k0 = *(const f16x8*)&Kl[cur][l31 * 64 + 8 * ((hi + 2 * ds) ^ e7)];
      f16x8 k1 = *(const f16x8*)&Kl[cur][(32 + l31) * 64 + 8 * ((hi + 2 * ds) ^ e7)];
      s0 = mfma32(k0, qf[ds], s0);
      s1 = mfma32(k1, qf[ds], s1);
    }
    __builtin_amdgcn_s_setprio(0);

    if (kt == 7) {
#pragma unroll
      for (int r = 0; r < 16; ++r) {
        int kvL = (r & 3) + 8 * (r >> 2) + 4 * hi;
        if (480 + kvL >= 500) s1[r] = -1e30f;
      }
    }

    float ps = 0.f;
#pragma unroll
    for (int r = 0; r < 16; ++r) {
      float t = __builtin_amdgcn_exp2f(s0[r]);
      s0[r] = t; ps += t;
    }
#pragma unroll
    for (int r = 0; r < 16; ++r) {
      float t = __builtin_amdgcn_exp2f(s1[r]);
      s1[r] = t; ps += t;
    }
    l += ps;

    f16x8 pf0 = mkfrag(s0[0], s0[1], s0[2], s0[3], s0[4], s0[5], s0[6], s0[7]);
    f16x8 pf1 = mkfrag(s0[8], s0[9], s0[10], s0[11], s0[12], s0[13], s0[14], s0[15]);
    f16x8 pf2 = mkfrag(s1[0], s1[1], s1[2], s1[3], s1[4], s1[5], s1[6], s1[7]);
    f16x8 pf3 = mkfrag(s1[8], s1[9], s1[10], s1[11], s1[12], s1[13], s1[14], s1[15]);

    __builtin_amdgcn_s_setprio(1);
#pragma unroll
    for (int ks = 0; ks < 4; ++ks) {
      f16x8 pf = ks == 0 ? pf0 : ks == 1 ? pf1 : ks == 2 ? pf2 : pf3;
      int sw = (16 * ks + 8 * hi) ^ (e7 << 3);
      f16x8 v0 = *(const f16x8*)&VT[cur][l31 * 64 + sw];
      f16x8 v1 = *(const f16x8*)&VT[cur][(32 + l31) * 64 + sw];
      O0 = mfma32(pf, v0, O0);
      O1 = mfma32(pf, v1, O1);
    }
    __builtin_amdgcn_s_setprio(0);

    if (kt < 7) {
#pragma unroll
      for (int dd = 0; dd < 4; ++dd) {
        int d = d4 + dd;
        *(u32*)&VT[nxt][d * 64 + (kvp ^ ((d & 7) << 3))] = pkh(va[dd], vb[dd]);
      }
    }
    __syncthreads();
  }

  float lt = l + __shfl_xor(l, 32);
  float linv = __builtin_amdgcn_rcpf(lt);
#pragma unroll
  for (int r = 0; r < 16; ++r) {
    int rowv = (r & 3) + 8 * (r >> 2) + 4 * hi;
    float li = __shfl(linv, rowv);
    int t = qt * 256 + w * 32 + rowv;
    if (t < 500) {
      size_t rowb = (size_t)(b * 500 + t) * 512 + h * 64;
      Yg[rowb + l31]      = (f16)(O0[r] * li);
      Yg[rowb + 32 + l31] = (f16)(O1[r] * li);
    }
  }
}

// ---------------------------------------------------------------------------
extern "C" void kernel_launch(void* const* d_in, const int* in_sizes, int n_in,
                              void* d_out, int out_size, void* d_ws, size_t ws_size,
                              hipStream_t stream) {
  const float* x      = (const float*)d_in[0];
  const float* w_attn = (const float*)d_in[1];
  const float* b_attn = (const float*)d_in[2];
  const float* w_proj = (const float*)d_in[3];
  const float* b_proj = (const float*)d_in[4];
  float* out = (float*)d_out;

  char* wsp = (char*)d_ws;
  f16* Yg   = (f16*)wsp;                       // [32000][512]
  f16* qkv  = (f16*)(wsp + 32768000);          // [32000][1536]
  f16* wa_h = (f16*)(wsp + 32768000 + 98304000);
  f16* wp_h = (f16*)(wsp + 32768000 + 98304000 + 786432);
  if (ws_size < 132382720) return;

  // weights f32 -> f16 (655360 elems, 320 blocks)
  cvt_w<<<320, dim3(256), 0, stream>>>(w_attn, wa_h, w_proj, wp_h);

  // qkv = x(f32) @ wa^T + b_attn, fused A-cvt (M=32000 N=1536 K=256): 1500
  gemm1fa<<<1500, dim3(512), 0, stream>>>(x, wa_h, b_attn, qkv);
  // flash attention -> Yg [32000][512] f16
  attn_kern<<<1024, dim3(512), 0, stream>>>(qkv, Yg);
  // out = Yg @ wp^T + b_proj (M=32000 N=512 K=512): 250x4 = 1000
  gemmdb<1, 512, 512><<<1000, dim3(512), 0, stream>>>(Yg, wp_h, b_proj, nullptr, out);
}

// Round 20
// 130.740 us; speedup vs baseline: 1.1143x; 1.1143x over previous
//
#include <hip/hip_runtime.h>

typedef _Float16 f16;
typedef _Float16 f16x8 __attribute__((ext_vector_type(8)));
typedef _Float16 f16x4 __attribute__((ext_vector_type(4)));
typedef _Float16 f16x2 __attribute__((ext_vector_type(2)));
typedef __fp16   h16x2 __attribute__((ext_vector_type(2)));
typedef float    f32x16 __attribute__((ext_vector_type(16)));
typedef unsigned int u32;

typedef const __attribute__((address_space(1))) void GVOID;
typedef __attribute__((address_space(3))) void LVOID;

static __device__ __forceinline__ f32x16 mfma32(f16x8 a, f16x8 b, f32x16 c) {
  return __builtin_amdgcn_mfma_f32_32x32x16_f16(a, b, c, 0, 0, 0);
}
static __device__ __forceinline__ void gl_lds16(const f16* g, f16* l) {
  __builtin_amdgcn_global_load_lds((GVOID*)g, (LVOID*)l, 16, 0, 0);
}
// single-instruction packed f32x2 -> f16x2 (RTZ)
static __device__ __forceinline__ u32 pk(float a, float b) {
  union { h16x2 h; u32 w; } u;
  u.h = __builtin_amdgcn_cvt_pkrtz(a, b);
  return u.w;
}
static __device__ __forceinline__ u32 pkh(f16 a, f16 b) {
  union { f16x2 h; u32 w; } u;
  u.h[0] = a; u.h[1] = b;
  return u.w;
}
// A-frag builder: 8 P values -> f16x8 = P[q][kv=8*hi+j] via permlane32_swap.
static __device__ __forceinline__ f16x8 mkfrag(float a0, float a1, float a2, float a3,
                                               float a4, float a5, float a6, float a7) {
  u32 c01 = pk(a0, a1), c23 = pk(a2, a3), c45 = pk(a4, a5), c67 = pk(a6, a7);
  asm("v_permlane32_swap_b32 %0, %1" : "+v"(c01), "+v"(c45));
  asm("v_permlane32_swap_b32 %0, %1" : "+v"(c23), "+v"(c67));
  union { f16x8 h; u32 w[4]; } u;
  u.w[0] = c01; u.w[1] = c23; u.w[2] = c45; u.w[3] = c67;
  return u.h;
}

// ---------------------------------------------------------------------------
// fused f32 -> f16 convert for x, w_attn, w_proj (one launch)  [r16 exact]
// ---------------------------------------------------------------------------
__global__ __launch_bounds__(256)
void cvt_all(const float* __restrict__ x,  f16* __restrict__ xh,
             const float* __restrict__ wa, f16* __restrict__ wah,
             const float* __restrict__ wp, f16* __restrict__ wph) {
  int i = (blockIdx.x * 256 + threadIdx.x) * 8;
  const float* s; f16* d;
  if (i < 8192000)            { s = x + i;                 d = xh + i; }
  else if (i < 8192000+393216){ int j = i - 8192000;       s = wa + j; d = wah + j; }
  else                        { int j = i - 8585216;       s = wp + j; d = wph + j; }
  float4 v0 = *(const float4*)(s);
  float4 v1 = *(const float4*)(s + 4);
  f16x8 h;
  h[0] = (f16)v0.x; h[1] = (f16)v0.y; h[2] = (f16)v0.z; h[3] = (f16)v0.w;
  h[4] = (f16)v1.x; h[5] = (f16)v1.y; h[6] = (f16)v1.z; h[7] = (f16)v1.w;
  *(f16x8*)d = h;
}

// ---------------------------------------------------------------------------
// GEMM1 [r16 gemm256 exact]: 256x128 tile, BK=64, 8 waves of 64x64, gl_lds.
// ---------------------------------------------------------------------------
template<int EPI, int KD, int NDIM>
__global__ __launch_bounds__(512)
void gemm256(const f16* __restrict__ A, const f16* __restrict__ B,
             const float* __restrict__ bias, f16* __restrict__ outH,
             float* __restrict__ outF) {
  constexpr int NB = NDIM / 128;
  const int nwg = gridDim.x;
  const int orig = blockIdx.x;
  const int xcd = orig & 7, loc = orig >> 3;
  const int qq = nwg >> 3, rr8 = nwg & 7;
  const int g = (xcd < rr8 ? xcd * (qq + 1) : rr8 * (qq + 1) + (xcd - rr8) * qq) + loc;
  const int mb = g / NB, nb = g - mb * NB;
  const int m0 = mb * 256, n0 = nb * 128;

  __shared__ __align__(16) f16 As[256 * 64];
  __shared__ __align__(16) f16 Bs[128 * 64];
  const int tid = threadIdx.x, wid = tid >> 6;
  const int l31 = tid & 31, hi = (tid >> 5) & 1;
  const int wm = (wid >> 1) * 64, wn = (wid & 1) * 64;

  f32x16 acc[2][2] = {};

  for (int k0 = 0; k0 < KD; k0 += 64) {
    __syncthreads();
#pragma unroll
    for (int i = 0; i < 4; ++i) {
      int c = i * 512 + tid, row = c >> 3;
      int col = 8 * ((c & 7) ^ (row & 7));
      gl_lds16(A + (size_t)(m0 + row) * KD + k0 + col, &As[c * 8]);
    }
#pragma unroll
    for (int i = 0; i < 2; ++i) {
      int c = i * 512 + tid, row = c >> 3;
      int col = 8 * ((c & 7) ^ (row & 7));
      gl_lds16(B + (size_t)(n0 + row) * KD + k0 + col, &Bs[c * 8]);
    }
    __syncthreads();
#pragma unroll
    for (int kk = 0; kk < 4; ++kk) {
      f16x8 af[2], bf[2];
#pragma unroll
      for (int t = 0; t < 2; ++t) {
        int ra = wm + t * 32 + l31;
        af[t] = *(const f16x8*)&As[ra * 64 + 8 * ((2 * kk + hi) ^ (ra & 7))];
        int rb = wn + t * 32 + l31;
        bf[t] = *(const f16x8*)&Bs[rb * 64 + 8 * ((2 * kk + hi) ^ (rb & 7))];
      }
#pragma unroll
      for (int ms = 0; ms < 2; ++ms)
#pragma unroll
        for (int ns = 0; ns < 2; ++ns)
          acc[ms][ns] = mfma32(af[ms], bf[ns], acc[ms][ns]);
    }
  }

  float bv[2];
  bv[0] = bias[n0 + wn + l31];
  bv[1] = bias[n0 + wn + 32 + l31];
#pragma unroll
  for (int ms = 0; ms < 2; ++ms)
#pragma unroll
    for (int ns = 0; ns < 2; ++ns)
#pragma unroll
      for (int r = 0; r < 16; ++r) {
        int mrow = (r & 3) + 8 * (r >> 2) + 4 * hi;
        int m_g = m0 + wm + ms * 32 + mrow;
        int n_g = n0 + wn + ns * 32 + l31;
        float v = acc[ms][ns][r] + bv[ns];
        if (EPI == 0) outH[(size_t)m_g * NDIM + n_g] = (f16)v;
        else          outF[(size_t)m_g * NDIM + n_g] = v;
      }
}

// ---------------------------------------------------------------------------
// GEMM3 [gemmdb exact]: 128x128, BK=64, 8 waves, dbuf, counted vmcnt.
// ---------------------------------------------------------------------------
template<int EPI, int KD, int NDIM>
__global__ __launch_bounds__(512)
void gemmdb(const f16* __restrict__ A, const f16* __restrict__ B,
            const float* __restrict__ bias, f16* __restrict__ outH,
            float* __restrict__ outF) {
  constexpr int KT = KD / 64;
  constexpr int ABUF = 128 * 64, BUFSZ = 2 * ABUF;
  __shared__ __align__(16) f16 lds[2 * BUFSZ];

  const int nwg = gridDim.x, orig = blockIdx.x;
  const int xcd = orig & 7, loc = orig >> 3;
  const int qq = nwg >> 3, rr8 = nwg & 7;
  const int gb = (xcd < rr8 ? xcd * (qq + 1) : rr8 * (qq + 1) + (xcd - rr8) * qq) + loc;
  constexpr int NB = NDIM / 128;
  const int mb = gb / NB, nb = gb - mb * NB;
  const int m0 = mb * 128, n0 = nb * 128;

  const int tid = threadIdx.x, wid = tid >> 6;
  const int l31 = tid & 31, hi = (tid >> 5) & 1;
  const int wm = (wid >> 2) * 64, wn = (wid & 3) * 32;

  f32x16 acc[2] = {};

  const int c0 = tid, c1 = 512 + tid;
  const int r0 = c0 >> 3, col0 = 8 * ((c0 & 7) ^ (r0 & 7));
  const int r1 = c1 >> 3, col1 = 8 * ((c1 & 7) ^ (r1 & 7));

  auto STAGE = [&](int t, int bufi) {
    const int k0 = t * 64;
    f16* Ab = &lds[bufi * BUFSZ];
    f16* Bb = Ab + ABUF;
    gl_lds16(A + (size_t)(m0 + r0) * KD + k0 + col0, &Ab[c0 * 8]);
    gl_lds16(A + (size_t)(m0 + r1) * KD + k0 + col1, &Ab[c1 * 8]);
    gl_lds16(B + (size_t)(n0 + r0) * KD + k0 + col0, &Bb[c0 * 8]);
    gl_lds16(B + (size_t)(n0 + r1) * KD + k0 + col1, &Bb[c1 * 8]);
  };

  STAGE(0, 0);
  int cur = 0;
#pragma unroll
  for (int t = 0; t < KT; ++t) {
    if (t + 1 < KT) {
      STAGE(t + 1, cur ^ 1);
      asm volatile("s_waitcnt vmcnt(4)" ::: "memory");
    } else {
      asm volatile("s_waitcnt vmcnt(0)" ::: "memory");
    }
    __builtin_amdgcn_sched_barrier(0);
    __builtin_amdgcn_s_barrier();

    const f16* Ab = &lds[cur * BUFSZ];
    const f16* Bb = Ab + ABUF;
    __builtin_amdgcn_s_setprio(1);
#pragma unroll
    for (int kk = 0; kk < 4; ++kk) {
      int rb = wn + l31;
      f16x8 bf = *(const f16x8*)&Bb[rb * 64 + 8 * ((2 * kk + hi) ^ (rb & 7))];
      int ra0 = wm + l31, ra1 = wm + 32 + l31;
      f16x8 af0 = *(const f16x8*)&Ab[ra0 * 64 + 8 * ((2 * kk + hi) ^ (ra0 & 7))];
      f16x8 af1 = *(const f16x8*)&Ab[ra1 * 64 + 8 * ((2 * kk + hi) ^ (ra1 & 7))];
      acc[0] = mfma32(af0, bf, acc[0]);
      acc[1] = mfma32(af1, bf, acc[1]);
    }
    __builtin_amdgcn_s_setprio(0);
    __builtin_amdgcn_s_barrier();
    cur ^= 1;
  }

  float bv = bias[n0 + wn + l31];
#pragma unroll
  for (int ms = 0; ms < 2; ++ms)
#pragma unroll
    for (int r = 0; r < 16; ++r) {
      int mrow = (r & 3) + 8 * (r >> 2) + 4 * hi;
      int m_g = m0 + wm + ms * 32 + mrow;
      int n_g = n0 + wn + l31;
      float v = acc[ms][r] + bv;
      if (EPI == 0) outH[(size_t)m_g * NDIM + n_g] = (f16)v;
      else          outF[(size_t)m_g * NDIM + n_g] = v;
    }
}

// ---------------------------------------------------------------------------
// Flash attention [r18/r19 exact]: full unroll, lane-local l, kt==6-only
// clamps, cvt_pkrtz pk.
// ---------------------------------------------------------------------------
__global__ __launch_bounds__(512, 4)
void attn_kern(const f16* __restrict__ qkv, f16* __restrict__ Yg) {
  __shared__ __align__(16) f16 Kl[2][64 * 64];
  __shared__ __align__(16) f16 VT[2][64 * 64];
  const int id = blockIdx.x;
  const int g = (id & 7) * 128 + (id >> 3);
  const int bh = g >> 1, qt = g & 1;
  const int b = bh >> 3, h = bh & 7;
  const int tid = threadIdx.x, w = tid >> 6;
  const int l31 = tid & 31, hi = (tid & 63) >> 5, e7 = l31 & 7;

  const f16* base  = qkv + (size_t)b * 500 * 1536 + h * 64;
  const f16* Kbase = base + 512;
  const f16* Vbase = base + 1024;

  const int q = qt * 256 + w * 32 + l31;
  const int qc = q < 500 ? q : 499;
  f16x8 qf[4];
  const f16* qp = base + (size_t)qc * 1536 + hi * 8;
#pragma unroll
  for (int ds = 0; ds < 4; ++ds) qf[ds] = *(const f16x8*)(qp + 16 * ds);
  const f16 qs = (f16)(0.125f * 1.44269504f);
#pragma unroll
  for (int ds = 0; ds < 4; ++ds)
#pragma unroll
    for (int j = 0; j < 8; ++j) qf[ds][j] *= qs;

  f32x16 O0 = {}, O1 = {};
  float l = 0.f;

  const int krow = tid >> 3, kcol = 8 * ((tid & 7) ^ (krow & 7));
  const int kvp = (tid & 31) * 2, d4 = (tid >> 5) * 4;
  f16x4 va, vb;
  const f16x4 VZ4 = {};

  {
    gl_lds16(Kbase + (size_t)krow * 1536 + kcol, &Kl[0][tid * 8]);
    const f16* vp0 = Vbase + (size_t)kvp * 1536 + d4;
    va = *(const f16x4*)vp0; vb = *(const f16x4*)(vp0 + 1536);
#pragma unroll
    for (int dd = 0; dd < 4; ++dd) {
      int d = d4 + dd;
      *(u32*)&VT[0][d * 64 + (kvp ^ ((d & 7) << 3))] = pkh(va[dd], vb[dd]);
    }
    __syncthreads();
  }

#pragma unroll
  for (int kt = 0; kt < 8; ++kt) {
    const int cur = kt & 1, nxt = cur ^ 1;
    if (kt < 7) {
      const int kvn = (kt + 1) * 64;
      int kr = kvn + krow;
      if (kt == 6) kr = kr < 500 ? kr : 499;
      gl_lds16(Kbase + (size_t)kr * 1536 + kcol, &Kl[nxt][tid * 8]);
      int kv = kvn + kvp;
      if (kt == 6) {
        int kc0 = kv < 500 ? kv : 499, kc1 = kv + 1 < 500 ? kv + 1 : 499;
        va = *(const f16x4*)(Vbase + (size_t)kc0 * 1536 + d4);
        vb = *(const f16x4*)(Vbase + (size_t)kc1 * 1536 + d4);
        if (kv >= 500) va = VZ4;
        if (kv + 1 >= 500) vb = VZ4;
      } else {
        va = *(const f16x4*)(Vbase + (size_t)kv * 1536 + d4);
        vb = *(const f16x4*)(Vbase + (size_t)(kv + 1) * 1536 + d4);
      }
    }

    f32x16 s0 = {}, s1 = {};
    __builtin_amdgcn_s_setprio(1);
#pragma unroll
    for (int ds = 0; ds < 4; ++ds) {
      f16x8 k0 = *(const f16x8*)&Kl[cur][l31 * 64 + 8 * ((hi + 2 * ds) ^ e7)];
      f16x8 k1 = *(const f16x8*)&Kl[cur][(32 + l31) * 64 + 8 * ((hi + 2 * ds) ^ e7)];
      s0 = mfma32(k0, qf[ds], s0);
      s1 = mfma32(k1, qf[ds], s1);
    }
    __builtin_amdgcn_s_setprio(0);

    if (kt == 7) {
#pragma unroll
      for (int r = 0; r < 16; ++r) {
        int kvL = (r & 3) + 8 * (r >> 2) + 4 * hi;
        if (480 + kvL >= 500) s1[r] = -1e30f;
      }
    }

    float ps = 0.f;
#pragma unroll
    for (int r = 0; r < 16; ++r) {
      float t = __builtin_amdgcn_exp2f(s0[r]);
      s0[r] = t; ps += t;
    }
#pragma unroll
    for (int r = 0; r < 16; ++r) {
      float t = __builtin_amdgcn_exp2f(s1[r]);
      s1[r] = t; ps += t;
    }
    l += ps;

    f16x8 pf0 = mkfrag(s0[0], s0[1], s0[2], s0[3], s0[4], s0[5], s0[6], s0[7]);
    f16x8 pf1 = mkfrag(s0[8], s0[9], s0[10], s0[11], s0[12], s0[13], s0[14], s0[15]);
    f16x8 pf2 = mkfrag(s1[0], s1[1], s1[2], s1[3], s1[4], s1[5], s1[6], s1[7]);
    f16x8 pf3 = mkfrag(s1[8], s1[9], s1[10], s1[11], s1[12], s1[13], s1[14], s1[15]);

    __builtin_amdgcn_s_setprio(1);
#pragma unroll
    for (int ks = 0; ks < 4; ++ks) {
      f16x8 pf = ks == 0 ? pf0 : ks == 1 ? pf1 : ks == 2 ? pf2 : pf3;
      int sw = (16 * ks + 8 * hi) ^ (e7 << 3);
      f16x8 v0 = *(const f16x8*)&VT[cur][l31 * 64 + sw];
      f16x8 v1 = *(const f16x8*)&VT[cur][(32 + l31) * 64 + sw];
      O0 = mfma32(pf, v0, O0);
      O1 = mfma32(pf, v1, O1);
    }
    __builtin_amdgcn_s_setprio(0);

    if (kt < 7) {
#pragma unroll
      for (int dd = 0; dd < 4; ++dd) {
        int d = d4 + dd;
        *(u32*)&VT[nxt][d * 64 + (kvp ^ ((d & 7) << 3))] = pkh(va[dd], vb[dd]);
      }
    }
    __syncthreads();
  }

  float lt = l + __shfl_xor(l, 32);
  float linv = __builtin_amdgcn_rcpf(lt);
#pragma unroll
  for (int r = 0; r < 16; ++r) {
    int rowv = (r & 3) + 8 * (r >> 2) + 4 * hi;
    float li = __shfl(linv, rowv);
    int t = qt * 256 + w * 32 + rowv;
    if (t < 500) {
      size_t rowb = (size_t)(b * 500 + t) * 512 + h * 64;
      Yg[rowb + l31]      = (f16)(O0[r] * li);
      Yg[rowb + 32 + l31] = (f16)(O1[r] * li);
    }
  }
}

// ---------------------------------------------------------------------------
extern "C" void kernel_launch(void* const* d_in, const int* in_sizes, int n_in,
                              void* d_out, int out_size, void* d_ws, size_t ws_size,
                              hipStream_t stream) {
  const float* x      = (const float*)d_in[0];
  const float* w_attn = (const float*)d_in[1];
  const float* b_attn = (const float*)d_in[2];
  const float* w_proj = (const float*)d_in[3];
  const float* b_proj = (const float*)d_in[4];
  float* out = (float*)d_out;

  char* wsp = (char*)d_ws;
  f16* Yg   = (f16*)wsp;                       // [32000][512] (aliases x_h)
  f16* x_h  = (f16*)wsp;
  f16* qkv  = (f16*)(wsp + 32768000);          // [32000][1536]
  f16* wa_h = (f16*)(wsp + 32768000 + 98304000);
  f16* wp_h = (f16*)(wsp + 32768000 + 98304000 + 786432);
  if (ws_size < 132382720) return;

  cvt_all<<<4320, dim3(256), 0, stream>>>(x, x_h, w_attn, wa_h, w_proj, wp_h);

  // qkv = x @ w_attn^T + b_attn   (M=32000, N=1536, K=256): 125x12 = 1500
  gemm256<0, 256, 1536><<<1500, dim3(512), 0, stream>>>(x_h, wa_h, b_attn, qkv, nullptr);
  // flash attention -> Yg [32000][512] f16
  attn_kern<<<1024, dim3(512), 0, stream>>>(qkv, Yg);
  // out = Yg @ w_proj^T + b_proj  (M=32000, N=512, K=512): 250x4 = 1000
  gemmdb<1, 512, 512><<<1000, dim3(512), 0, stream>>>(Yg, wp_h, b_proj, nullptr, out);
}